// Round 2
// baseline (25322.847 us; speedup 1.0000x reference)
//
#include <hip/hip_runtime.h>
#include <math.h>

#define HID   512
#define SEQL  256
#define BATCH 2048
#define NCLS  10
#define NB    16      // batch cols per WG -> one 16-wide MFMA N-tile
#define NKB   17      // 16 k-blocks of h + 1 augmented block [x;1;0...]
#define NMT   128     // 2048 gate-rows / 16

typedef __attribute__((ext_vector_type(8))) short  short8;
typedef __attribute__((ext_vector_type(4))) float  f32x4;

static __device__ __forceinline__ unsigned short f2bf(float f) {
    unsigned u = __builtin_bit_cast(unsigned, f);
    unsigned r = (u + 0x7FFFu + ((u >> 16) & 1u)) >> 16;   // RNE
    return (unsigned short)r;
}
static __device__ __forceinline__ float sigm(float v) {
    return __builtin_amdgcn_rcpf(1.f + __expf(-v));
}
static __device__ __forceinline__ float tanh_fast(float v) {
    // 1 - 2/(1+e^{2v}) : v_exp + fma + rcp + fma
    return fmaf(-2.f, __builtin_amdgcn_rcpf(1.f + __expf(2.f * v)), 1.f);
}

// ---------------------------------------------------------------------------
// Pack weights into exact MFMA A-fragment order, bf16:
//   Apre[((mt*NKB + kb)*64 + lane)*8 + j8] = A[mt*16 + (lane&15)][kb*32 + (lane>>4)*8 + j8]
// Rows 0..2047 = [g | i | f | o] x 512. kb==16 is the augmentation block:
// k=512 -> wgx[row], k=513 -> bias[row], k=514..543 -> 0.
// ---------------------------------------------------------------------------
__global__ void build_A(const float* __restrict__ wgh, const float* __restrict__ wih,
                        const float* __restrict__ wfh, const float* __restrict__ woh,
                        const float* __restrict__ wgx, const float* __restrict__ wix,
                        const float* __restrict__ wfx, const float* __restrict__ wox,
                        const float* __restrict__ bg,  const float* __restrict__ bi,
                        const float* __restrict__ bf_, const float* __restrict__ bo,
                        unsigned short* __restrict__ Apre)
{
    const int kb   = blockIdx.x;          // 0..16
    const int mt   = blockIdx.y;          // 0..127
    const int lane = threadIdx.x;         // 0..63
    const int m    = lane & 15;
    const int quad = lane >> 4;
    const int row  = mt * 16 + m;
    const int gate = row >> 9;            // uniform per block (tiles are 16-aligned)
    const int j    = row & 511;

    const float* W[4]  = {wgh, wih, wfh, woh};
    const float* Wx[4] = {wgx, wix, wfx, wox};
    const float* Bs[4] = {bg,  bi,  bf_, bo};

    unsigned short tmp[8];
    #pragma unroll
    for (int j8 = 0; j8 < 8; j8++) {
        const int k = kb * 32 + quad * 8 + j8;
        float v;
        if (kb < 16) {
            v = W[gate][j * HID + k];
        } else {
            const int kk = k - HID;
            v = (kk == 0) ? Wx[gate][j] : (kk == 1) ? Bs[gate][j] : 0.f;
        }
        tmp[j8] = f2bf(v);
    }
    short8* dst = (short8*)(Apre + (((size_t)mt * NKB + kb) * 64 + lane) * 8);
    *dst = *(const short8*)tmp;
}

// ---------------------------------------------------------------------------
// Persistent MFMA LSTM: WG owns 16 batch cols for all 256 steps.
// Wave w handles m-tiles {w*4+m : m<4} within EACH gate -> hidden rows
// j = w*64 + m*16 + quad*4 + r, col = lane&15 per lane.
// ---------------------------------------------------------------------------
__global__ __launch_bounds__(512, 2) void lstm_mfma(
    const float* __restrict__ x,                 // [B][SEQ]
    const unsigned short* __restrict__ Apre,     // packed weights
    const float* __restrict__ wph, const float* __restrict__ bp,
    const float* __restrict__ h_init, const float* __restrict__ c_init,
    float* __restrict__ out)                     // [B][C]
{
    __shared__ char pool[32768];
    unsigned short* hB  = (unsigned short*)pool;           // 16 KB: B-frag bf16 h
    float*          x_s = (float*)(pool + 16384);          // 16 KB: x [t][col]
    float*          h32 = (float*)pool;                    // 32 KB alias (epilogue)

    const int tid  = threadIdx.x;
    const int wave = tid >> 6;
    const int lane = tid & 63;
    const int col  = lane & 15;
    const int quad = lane >> 4;
    const int b0   = blockIdx.x * NB;

    for (int i = tid; i < SEQL * NB; i += 512) {
        const int t = i >> 4, c = i & 15;
        x_s[i] = x[(b0 + c) * SEQL + t];
    }
    // h_init broadcast over cols, laid out in B-fragment order
    for (int i = tid; i < 16 * 512; i += 512) {
        const int kb = i >> 9, l = (i >> 3) & 63, j8 = i & 7;
        const int k  = kb * 32 + ((l >> 4) << 3) + j8;
        hB[i] = f2bf(h_init[k]);
    }

    float c_reg[4][4], hnew[4][4];
    #pragma unroll
    for (int m = 0; m < 4; m++)
        #pragma unroll
        for (int r = 0; r < 4; r++)
            c_reg[m][r] = c_init[wave * 64 + m * 16 + quad * 4 + r];
    __syncthreads();

    for (int t = 0; t < SEQL; t++) {
        // --- load B fragments (h) from LDS into registers ---
        short8 Bfrag[16];
        #pragma unroll
        for (int kb = 0; kb < 16; kb++)
            Bfrag[kb] = *(const short8*)(hB + kb * 512 + lane * 8);
        // augmented block: B[512][col]=x_t[col], B[513][col]=1
        short8 Bx = 0;
        if (quad == 0) {
            Bx[0] = (short)f2bf(x_s[t * 16 + col]);
            Bx[1] = (short)0x3F80;   // 1.0 bf16
        }
        __syncthreads();   // all lanes done reading hB for step t

        #pragma unroll
        for (int m = 0; m < 4; m++) {
            const int mtb = wave * 4 + m;   // tile-in-gate 0..31
            f32x4 ag = {0,0,0,0}, ai = {0,0,0,0}, af = {0,0,0,0}, ao = {0,0,0,0};
            #pragma unroll
            for (int kb = 0; kb < NKB; kb++) {
                const short8 b = (kb < 16) ? Bfrag[kb] : Bx;
                const short8 wg = *(const short8*)(Apre + (((size_t)(  0 + mtb) * NKB + kb) * 64 + lane) * 8);
                const short8 wi = *(const short8*)(Apre + (((size_t)( 32 + mtb) * NKB + kb) * 64 + lane) * 8);
                const short8 wf = *(const short8*)(Apre + (((size_t)( 64 + mtb) * NKB + kb) * 64 + lane) * 8);
                const short8 wo = *(const short8*)(Apre + (((size_t)( 96 + mtb) * NKB + kb) * 64 + lane) * 8);
                ag = __builtin_amdgcn_mfma_f32_16x16x32_bf16(wg, b, ag, 0, 0, 0);
                ai = __builtin_amdgcn_mfma_f32_16x16x32_bf16(wi, b, ai, 0, 0, 0);
                af = __builtin_amdgcn_mfma_f32_16x16x32_bf16(wf, b, af, 0, 0, 0);
                ao = __builtin_amdgcn_mfma_f32_16x16x32_bf16(wo, b, ao, 0, 0, 0);
            }
            #pragma unroll
            for (int r = 0; r < 4; r++) {
                const float g  = tanh_fast(ag[r]);
                const float ii = sigm(ai[r]);
                const float ff = sigm(af[r]);
                const float oo = sigm(ao[r]);
                const float cc = fmaf(c_reg[m][r], ff, g * ii);
                c_reg[m][r] = cc;
                const float h = tanh_fast(cc) * oo;
                hnew[m][r] = h;
                // write back into B-fragment layout (2-way bank alias = free)
                const int j = wave * 64 + m * 16 + quad * 4 + r;
                hB[(j >> 5) * 512 + (((((j >> 3) & 3) << 4) | col) * 8) + (j & 7)] = f2bf(h);
            }
        }
        __syncthreads();   // hB ready for step t+1
    }

    // --- epilogue: out = wph @ h + bp, fp32 from final register h ---
    #pragma unroll
    for (int m = 0; m < 4; m++)
        #pragma unroll
        for (int r = 0; r < 4; r++) {
            const int j = wave * 64 + m * 16 + quad * 4 + r;
            h32[j * 16 + col] = hnew[m][r];
        }
    __syncthreads();
    if (tid < NB * NCLS) {
        const int c = tid / NCLS, cls = tid % NCLS;
        float s = bp[cls];
        for (int k = 0; k < HID; k++)
            s = fmaf(wph[cls * HID + k], h32[k * 16 + c], s);
        out[(b0 + c) * NCLS + cls] = s;
    }
}

extern "C" void kernel_launch(void* const* d_in, const int* in_sizes, int n_in,
                              void* d_out, int out_size, void* d_ws, size_t ws_size,
                              hipStream_t stream)
{
    const float* x   = (const float*)d_in[0];
    const float* wgx = (const float*)d_in[1];
    const float* wix = (const float*)d_in[2];
    const float* wfx = (const float*)d_in[3];
    const float* wox = (const float*)d_in[4];
    const float* wgh = (const float*)d_in[5];
    const float* wih = (const float*)d_in[6];
    const float* wfh = (const float*)d_in[7];
    const float* woh = (const float*)d_in[8];
    const float* bg  = (const float*)d_in[9];
    const float* bi  = (const float*)d_in[10];
    const float* bf  = (const float*)d_in[11];
    const float* bo  = (const float*)d_in[12];
    const float* wph = (const float*)d_in[13];
    const float* bp  = (const float*)d_in[14];
    const float* h0  = (const float*)d_in[15];
    const float* c0  = (const float*)d_in[16];
    float* out = (float*)d_out;
    unsigned short* Apre = (unsigned short*)d_ws;   // 128*17*64*8*2 B = 2.23 MiB

    build_A<<<dim3(NKB, NMT), dim3(64), 0, stream>>>(
        wgh, wih, wfh, woh, wgx, wix, wfx, wox, bg, bi, bf, bo, Apre);
    lstm_mfma<<<dim3(BATCH / NB), dim3(512), 0, stream>>>(
        x, Apre, wph, bp, h0, c0, out);
}

// Round 3
// 16571.892 us; speedup vs baseline: 1.5281x; 1.5281x over previous
//
#include <hip/hip_runtime.h>
#include <math.h>

#define HID   512
#define SEQL  256
#define BATCH 2048
#define NCLS  10
#define NB    32      // batch cols per WG (2 MFMA n-tiles)
#define NKB   17      // 16 k-blocks of h + 1 augmented block [x;1;0...]

typedef __attribute__((ext_vector_type(8))) short  short8;
typedef __attribute__((ext_vector_type(4))) float  f32x4;

static __device__ __forceinline__ unsigned short f2bf(float f) {
    unsigned u = __builtin_bit_cast(unsigned, f);
    unsigned r = (u + 0x7FFFu + ((u >> 16) & 1u)) >> 16;   // RNE
    return (unsigned short)r;
}
static __device__ __forceinline__ float bf2f(unsigned short h) {
    unsigned u = ((unsigned)h) << 16;
    return __builtin_bit_cast(float, u);
}
static __device__ __forceinline__ float sigm(float v) {
    return __builtin_amdgcn_rcpf(1.f + __expf(-v));
}
static __device__ __forceinline__ float tanh_fast(float v) {
    return fmaf(-2.f, __builtin_amdgcn_rcpf(1.f + __expf(2.f * v)), 1.f);
}

// ---------------------------------------------------------------------------
// Pack weights into MFMA A-fragment order, bf16. Layout (shorts):
//   Apre[(((mt*NKB + kb)*4 + g)*64 + lane)*8 + j8]
//     = W[g][mt*16 + (lane&15)][kb*32 + (lane>>4)*8 + j8]
// mt in [0,32) = hidden-row tile, g = gate. kb==16 is the augmentation
// block: k=512 -> wx[g][row], k=513 -> bias[g][row], else 0.
// Total: 32*17*4*1KB = 2.176 MB (L2-resident).
// ---------------------------------------------------------------------------
__global__ void build_A(const float* __restrict__ wgh, const float* __restrict__ wih,
                        const float* __restrict__ wfh, const float* __restrict__ woh,
                        const float* __restrict__ wgx, const float* __restrict__ wix,
                        const float* __restrict__ wfx, const float* __restrict__ wox,
                        const float* __restrict__ bg,  const float* __restrict__ bi,
                        const float* __restrict__ bf_, const float* __restrict__ bo,
                        unsigned short* __restrict__ Apre)
{
    const int kb   = blockIdx.x;          // 0..16
    const int mt   = blockIdx.y;          // 0..31
    const int g    = blockIdx.z;          // 0..3
    const int lane = threadIdx.x;         // 0..63
    const int j    = mt * 16 + (lane & 15);
    const int quad = lane >> 4;

    const float* W[4]  = {wgh, wih, wfh, woh};
    const float* Wx[4] = {wgx, wix, wfx, wox};
    const float* Bs[4] = {bg,  bi,  bf_, bo};

    unsigned short tmp[8];
    #pragma unroll
    for (int j8 = 0; j8 < 8; j8++) {
        const int k = kb * 32 + quad * 8 + j8;
        float v;
        if (kb < 16) {
            v = W[g][j * HID + k];
        } else {
            const int kk = k - HID;
            v = (kk == 0) ? Wx[g][j] : (kk == 1) ? Bs[g][j] : 0.f;
        }
        tmp[j8] = f2bf(v);
    }
    short8* dst = (short8*)(Apre + ((((size_t)mt * NKB + kb) * 4 + g) * 64 + lane) * 8);
    *dst = *(const short8*)tmp;
}

// ---------------------------------------------------------------------------
// Persistent MFMA LSTM, 64 WGs x 512 threads, NB=32 cols each.
// Wave w owns m-tiles {w*4+mm}; per (m,kb): 4 gate A-frags x 2 n-tiles.
// Depth-3 manual weight prefetch keeps ~12 16B loads in flight per lane.
// ---------------------------------------------------------------------------
__global__ __launch_bounds__(512, 2) void lstm_mfma(
    const float* __restrict__ x,                 // [B][SEQ]
    const unsigned short* __restrict__ Apre,
    const float* __restrict__ wph, const float* __restrict__ bp,
    const float* __restrict__ h_init, const float* __restrict__ c_init,
    float* __restrict__ out)                     // [B][C]
{
    __shared__ unsigned short hB[2 * 16 * 512];   // 32 KB: B-frag bf16 h, 2 n-tiles
    __shared__ unsigned short x_s[SEQL * NB];     // 16 KB: x bf16 [t][col]

    const int tid  = threadIdx.x;
    const int wave = tid >> 6;
    const int lane = tid & 63;
    const int col  = lane & 15;
    const int quad = lane >> 4;
    const int b0   = blockIdx.x * NB;

    // x slice -> LDS (bf16), coalesced along t
    for (int i = tid; i < SEQL * NB; i += 512) {
        const int c = i >> 8, t = i & 255;
        x_s[t * NB + c] = f2bf(x[(b0 + c) * SEQL + t]);
    }
    // h_init broadcast in B-fragment order (same for both n-tiles)
    for (int i = tid; i < 2 * 16 * 512; i += 512) {
        const int rem = i & 8191;
        const int kb = rem >> 9, l = (rem >> 3) & 63, j8 = rem & 7;
        hB[i] = f2bf(h_init[kb * 32 + ((l >> 4) << 3) + j8]);
    }

    float c_reg[4][2][4];
    #pragma unroll
    for (int mm = 0; mm < 4; mm++) {
        const int j = (wave * 4 + mm) * 16 + quad * 4;
        #pragma unroll
        for (int r = 0; r < 4; r++) {
            const float c0 = c_init[j + r];
            c_reg[mm][0][r] = c0;
            c_reg[mm][1][r] = c0;
        }
    }
    __syncthreads();

    for (int t = 0; t < SEQL; t++) {
        // augmented-K B fragments: B[512][c]=x_t[c], B[513][c]=1
        short8 Bx0 = 0, Bx1 = 0;
        if (quad == 0) {
            Bx0[0] = (short)x_s[t * NB + col];
            Bx1[0] = (short)x_s[t * NB + 16 + col];
            Bx0[1] = (short)0x3F80;
            Bx1[1] = (short)0x3F80;
        }

        float hnew[4][2][4];
        #pragma unroll
        for (int mm = 0; mm < 4; mm++) {
            const int mt = wave * 4 + mm;
            const unsigned short* Aw = Apre + (size_t)mt * (NKB * 4 * 512) + lane * 8;
            short8 Wc[4], Wn[4];
            #pragma unroll
            for (int g = 0; g < 4; g++) {
                Wc[g] = *(const short8*)(Aw + 0 * 2048 + g * 512);
                Wn[g] = *(const short8*)(Aw + 1 * 2048 + g * 512);
            }
            f32x4 acc[4][2];
            #pragma unroll
            for (int g = 0; g < 4; g++) { acc[g][0] = (f32x4){0,0,0,0}; acc[g][1] = (f32x4){0,0,0,0}; }

            #pragma unroll
            for (int kb = 0; kb < NKB; kb++) {
                short8 Wf[4];
                if (kb < NKB - 2) {
                    #pragma unroll
                    for (int g = 0; g < 4; g++)
                        Wf[g] = *(const short8*)(Aw + (size_t)(kb + 2) * 2048 + g * 512);
                }
                short8 B0, B1;
                if (kb < 16) {
                    B0 = *(const short8*)(hB + kb * 512 + lane * 8);
                    B1 = *(const short8*)(hB + 8192 + kb * 512 + lane * 8);
                } else {
                    B0 = Bx0; B1 = Bx1;
                }
                #pragma unroll
                for (int g = 0; g < 4; g++) {
                    acc[g][0] = __builtin_amdgcn_mfma_f32_16x16x32_bf16(Wc[g], B0, acc[g][0], 0, 0, 0);
                    acc[g][1] = __builtin_amdgcn_mfma_f32_16x16x32_bf16(Wc[g], B1, acc[g][1], 0, 0, 0);
                }
                #pragma unroll
                for (int g = 0; g < 4; g++) { Wc[g] = Wn[g]; Wn[g] = Wf[g]; }
            }

            #pragma unroll
            for (int nt = 0; nt < 2; nt++)
                #pragma unroll
                for (int r = 0; r < 4; r++) {
                    const float g_  = tanh_fast(acc[0][nt][r]);
                    const float ii  = sigm(acc[1][nt][r]);
                    const float ff  = sigm(acc[2][nt][r]);
                    const float oo  = sigm(acc[3][nt][r]);
                    const float cc  = fmaf(c_reg[mm][nt][r], ff, g_ * ii);
                    c_reg[mm][nt][r] = cc;
                    hnew[mm][nt][r]  = tanh_fast(cc) * oo;
                }
        }
        __syncthreads();   // all waves done reading hB for step t

        #pragma unroll
        for (int mm = 0; mm < 4; mm++) {
            const int jb = (wave * 4 + mm) * 16 + quad * 4;
            #pragma unroll
            for (int nt = 0; nt < 2; nt++)
                #pragma unroll
                for (int r = 0; r < 4; r++) {
                    const int j = jb + r;
                    hB[nt * 8192 + (j >> 5) * 512 + ((((j >> 3) & 3) * 16 + col) * 8) + (j & 7)]
                        = f2bf(hnew[mm][nt][r]);
                }
        }
        __syncthreads();   // hB ready for step t+1
    }

    // epilogue: out[b][cls] = bp[cls] + sum_k wph[cls][k] * h[k][b]
    if (tid < NB * NCLS) {
        const int c = tid / NCLS, cls = tid % NCLS;
        float s = bp[cls];
        for (int k = 0; k < HID; k++) {
            const unsigned short hv =
                hB[(c >> 4) * 8192 + (k >> 5) * 512 + ((((k >> 3) & 3) * 16 + (c & 15)) * 8) + (k & 7)];
            s = fmaf(wph[cls * HID + k], bf2f(hv), s);
        }
        out[(b0 + c) * NCLS + cls] = s;
    }
}

extern "C" void kernel_launch(void* const* d_in, const int* in_sizes, int n_in,
                              void* d_out, int out_size, void* d_ws, size_t ws_size,
                              hipStream_t stream)
{
    const float* x   = (const float*)d_in[0];
    const float* wgx = (const float*)d_in[1];
    const float* wix = (const float*)d_in[2];
    const float* wfx = (const float*)d_in[3];
    const float* wox = (const float*)d_in[4];
    const float* wgh = (const float*)d_in[5];
    const float* wih = (const float*)d_in[6];
    const float* wfh = (const float*)d_in[7];
    const float* woh = (const float*)d_in[8];
    const float* bg  = (const float*)d_in[9];
    const float* bi  = (const float*)d_in[10];
    const float* bf  = (const float*)d_in[11];
    const float* bo  = (const float*)d_in[12];
    const float* wph = (const float*)d_in[13];
    const float* bp  = (const float*)d_in[14];
    const float* h0  = (const float*)d_in[15];
    const float* c0  = (const float*)d_in[16];
    float* out = (float*)d_out;
    unsigned short* Apre = (unsigned short*)d_ws;   // 32*17*4*64*8*2 B = 2.176 MiB

    build_A<<<dim3(NKB, 32, 4), dim3(64), 0, stream>>>(
        wgh, wih, wfh, woh, wgx, wix, wfx, wox, bg, bi, bf, bo, Apre);
    lstm_mfma<<<dim3(BATCH / NB), dim3(512), 0, stream>>>(
        x, Apre, wph, bp, h0, c0, out);
}